// Round 10
// baseline (161.284 us; speedup 1.0000x reference)
//
#include <hip/hip_runtime.h>
#include <math.h>

#define Bv 4
#define Tv 1024
#define Dv 1024
#define Hv 16
#define DHv 64
#define L2E 1.4426950408889634f

typedef __attribute__((ext_vector_type(8))) short short8;
typedef __attribute__((ext_vector_type(4))) short short4v;
typedef __attribute__((ext_vector_type(4))) float f32x4;
typedef __attribute__((ext_vector_type(2))) int int2v;

#define MFMA16(a, b, c) __builtin_amdgcn_mfma_f32_16x16x32_bf16((a), (b), (c), 0, 0, 0)

__device__ __forceinline__ short f2bf(float f) {
    union { float f; unsigned u; } v; v.f = f;
    unsigned r = v.u + 0x7FFFu + ((v.u >> 16) & 1u);
    return (short)(r >> 16);
}

// hardware exp2/log2 via compiler-known builtins (proper TRANS-hazard modeling)
__device__ __forceinline__ float exp2_hw(float x) {
#if __has_builtin(__builtin_amdgcn_exp2f)
    return __builtin_amdgcn_exp2f(x);
#else
    return exp2f(x);
#endif
}
__device__ __forceinline__ float log2_hw(float x) {
#if __has_builtin(__builtin_amdgcn_logf)
    return __builtin_amdgcn_logf(x);
#else
    return log2f(x);
#endif
}

// packed bf16 convert (RTNE, same rounding as f2bf). Non-TRANS VOP3: no hazard class.
__device__ __forceinline__ int cvt_pk_bf16(float lo, float hi) {
    int r; asm("v_cvt_pk_bf16_f32 %0, %1, %2" : "=v"(r) : "v"(lo), "v"(hi)); return r;
}

__device__ __forceinline__ void async16(const void* g, void* l) {
    __builtin_amdgcn_global_load_lds(
        (const __attribute__((address_space(1))) void*)g,
        (__attribute__((address_space(3))) void*)l, 16, 0, 0);
}

// Fragment read from a 64-short-wide tile stored with chunk-XOR swizzle
// (chunk cw of row r lives at slot cw ^ (r&7)). 2-way bank aliasing only.
__device__ __forceinline__ short8 frag64(const short* buf, int r, int cw) {
    return *(const short8*)&buf[r * 64 + ((cw ^ (r & 7)) << 3)];
}

// 32-short-wide (BK=32) variant: 4 chunks per row, slot = (cw ^ (r>>1)) & 3.
__device__ __forceinline__ short8 frag32(const short* buf, int r, int cw) {
    return *(const short8*)&buf[r * 32 + (((cw ^ (r >> 1)) & 3) << 3)];
}

// ---------------- prep: cast x -> xp panels AND cast+transpose W -> Wp panels ----------------
// Merged into one launch (saves a kernel launch + tail). Blocks [0,2048): x; [2048,2816): W.
__global__ __launch_bounds__(256) void prep(
    const float* __restrict__ x, const float* __restrict__ Wq,
    const float* __restrict__ Wk, const float* __restrict__ Wv,
    short* __restrict__ xp, short* __restrict__ Wp)
{
    const int bid = blockIdx.x;
    const int tid = threadIdx.x;
    if (bid < 2048) {
        const int idx = bid * 256 + tid;
        const int t = idx >> 7, j = idx & 127;
        const float* src = x + (size_t)t * 1024 + j * 8;
        float4 f0 = ((const float4*)src)[0], f1 = ((const float4*)src)[1];
        short8 o;
        o[0] = f2bf(f0.x); o[1] = f2bf(f0.y); o[2] = f2bf(f0.z); o[3] = f2bf(f0.w);
        o[4] = f2bf(f1.x); o[5] = f2bf(f1.y); o[6] = f2bf(f1.z); o[7] = f2bf(f1.w);
        *(short8*)&xp[(j >> 2) * 131072 + t * 32 + (j & 3) * 8] = o;
        return;
    }
    const int wb = bid - 2048;                // [0, 768)
    const int z = wb >> 8, rem = wb & 255;
    const int n0 = (rem & 15) * 64, k0 = (rem >> 4) * 64;
    const float* W = (z == 0) ? Wq : (z == 1) ? Wk : Wv;
    short* Wto = Wp + (size_t)z * 1048576;
    __shared__ short Tl[64 * 72];
    {
        const int r = tid >> 2, c16 = (tid & 3) * 16;
        const float* src = W + (size_t)(k0 + r) * Dv + n0 + c16;
        float4 f0 = ((const float4*)src)[0], f1 = ((const float4*)src)[1];
        float4 f2 = ((const float4*)src)[2], f3 = ((const float4*)src)[3];
        short8 s0, s1;
        s0[0] = f2bf(f0.x); s0[1] = f2bf(f0.y); s0[2] = f2bf(f0.z); s0[3] = f2bf(f0.w);
        s0[4] = f2bf(f1.x); s0[5] = f2bf(f1.y); s0[6] = f2bf(f1.z); s0[7] = f2bf(f1.w);
        s1[0] = f2bf(f2.x); s1[1] = f2bf(f2.y); s1[2] = f2bf(f2.z); s1[3] = f2bf(f2.w);
        s1[4] = f2bf(f3.x); s1[5] = f2bf(f3.y); s1[6] = f2bf(f3.z); s1[7] = f2bf(f3.w);
        *(short8*)&Tl[r * 72 + c16] = s0;
        *(short8*)&Tl[r * 72 + c16 + 8] = s1;
    }
    __syncthreads();
#pragma unroll
    for (int p = 0; p < 2; p++) {
        const int n = p * 32 + (tid >> 3), j8 = (tid & 7) * 8;
        short8 o;
#pragma unroll
        for (int jj = 0; jj < 8; jj++) o[jj] = Tl[(j8 + jj) * 72 + n];
        const int kk = k0 + j8;
        *(short8*)&Wto[(kk >> 5) * 32768 + (size_t)(n0 + n) * 32 + (kk & 31)] = o;
    }
}

// ---------------- QKV projection: merged-z 128x64 tile, BK=32, 2 blocks/CU ----------------
// (unchanged from round 9 -- deliberately frozen so the attn-side delta is attributable)
__global__ __launch_bounds__(256, 2) void qkv_mfma(
    const short* __restrict__ xp, const short* __restrict__ Wp,
    const float* __restrict__ bq, const float* __restrict__ bk, const float* __restrict__ bv,
    const float* __restrict__ temp,
    short* __restrict__ Qo, short* __restrict__ Kt, short* __restrict__ Vt)
{
    __shared__ short smem[30720];                // 3 slots x 10240 shorts = 60 KiB

    const int tid = threadIdx.x;
    const int lane = tid & 63, w = tid >> 6;
    const int q = lane >> 4, c = lane & 15;
    const int wr = w >> 1, wc = w & 1;           // 2x2 wave grid: 64 tok x 32 feat each
    const int n0 = blockIdx.x * 64, tm0 = blockIdx.y * 128;

    int aOff[2];
#pragma unroll
    for (int p = 0; p < 2; p++) {
        const int idx = p * 256 + tid;
        const int r = idx >> 2, cs = idx & 3, cg = (cs ^ (r >> 1)) & 3;
        aOff[p] = (tm0 + r) * 32 + cg * 8;
    }
    const int br = tid >> 2, bcs = tid & 3, bcg = (bcs ^ (br >> 1)) & 3;
    const int bOff = (n0 + br) * 32 + bcg * 8;

    f32x4 acc[3][4][2] = {};

    auto stage = [&](int s, int kb) {            // 5 loads/thread: A x2 + B x3
        short* base = smem + s * 10240;
#pragma unroll
        for (int p = 0; p < 2; p++)
            async16(xp + kb * 131072 + aOff[p], base + (p * 256 + tid) * 8);
#pragma unroll
        for (int z = 0; z < 3; z++)
            async16(Wp + z * 1048576 + kb * 32768 + bOff,
                    base + 4096 + z * 2048 + tid * 8);
    };
    auto compute = [&](int s) {
        const short* base = smem + s * 10240;
        short8 af[4];
#pragma unroll
        for (int m = 0; m < 4; m++) af[m] = frag32(base, wr * 64 + m * 16 + c, q);
        __builtin_amdgcn_s_setprio(1);
#pragma unroll
        for (int z = 0; z < 3; z++) {
            const short* Bz = base + 4096 + z * 2048;
            short8 b0 = frag32(Bz, wc * 32 + c, q);
            short8 b1 = frag32(Bz, wc * 32 + 16 + c, q);
#pragma unroll
            for (int m = 0; m < 4; m++) {
                acc[z][m][0] = MFMA16(af[m], b0, acc[z][m][0]);
                acc[z][m][1] = MFMA16(af[m], b1, acc[z][m][1]);
            }
        }
        __builtin_amdgcn_s_setprio(0);
    };

    stage(0, 0); stage(1, 1);                    // 10 loads (2 tiles) in flight

#pragma unroll 1
    for (int i = 0; i < 30; i++) {
        asm volatile("s_waitcnt vmcnt(5)" ::: "memory");   // tile i resident; i+1 in flight
        __builtin_amdgcn_s_barrier();
        __builtin_amdgcn_sched_barrier(0);
        stage((i + 2) % 3, i + 2);
        compute(i % 3);
    }
    asm volatile("s_waitcnt vmcnt(5)" ::: "memory");
    __builtin_amdgcn_s_barrier();
    __builtin_amdgcn_sched_barrier(0);
    compute(30 % 3);
    asm volatile("s_waitcnt vmcnt(0)" ::: "memory");
    __builtin_amdgcn_s_barrier();
    __builtin_amdgcn_sched_barrier(0);
    compute(31 % 3);

#pragma unroll
    for (int jn = 0; jn < 2; jn++) {
        const int col = n0 + wc * 32 + jn * 16 + c;
        const float bb = bq[col];
#pragma unroll
        for (int m = 0; m < 4; m++)
#pragma unroll
            for (int rr = 0; rr < 4; rr++) {
                const int row = tm0 + wr * 64 + m * 16 + q * 4 + rr;
                Qo[(size_t)row * Dv + col] = f2bf(acc[0][m][jn][rr] + bb);
            }
    }
    const int hb = tm0 >> 6;
#pragma unroll
    for (int z = 1; z < 3; z++) {
        const float* bias = (z == 1) ? bk : bv;
        short* dst = (z == 1) ? Kt : Vt;
        float scl = 1.f;
        if (z == 1) scl = temp[(hb + wr) & 15] * L2E;
        __syncthreads();
        short* T = smem;
#pragma unroll
        for (int jn = 0; jn < 2; jn++) {
            const int nl = wc * 32 + jn * 16 + c;
            const float bb = bias[n0 + nl];
#pragma unroll
            for (int m = 0; m < 4; m++) {
                int2v pk;
                pk[0] = cvt_pk_bf16((acc[z][m][jn][0] + bb) * scl, (acc[z][m][jn][1] + bb) * scl);
                pk[1] = cvt_pk_bf16((acc[z][m][jn][2] + bb) * scl, (acc[z][m][jn][3] + bb) * scl);
                *(int2v*)&T[nl * 136 + wr * 64 + m * 16 + q * 4] = pk;
            }
        }
        __syncthreads();
#pragma unroll
        for (int p = 0; p < 4; p++) {
            const int idx = p * 256 + tid;
            const int n = idx >> 4, k2 = idx & 15;
            short8 v = *(const short8*)&T[n * 136 + k2 * 8];
            const size_t addr = (size_t)(hb + (k2 >> 3)) * 65536 +
                                (size_t)(n0 + n) * 64 + (k2 & 7) * 8;
            *(short8*)&dst[addr] = v;
        }
    }
}

// ---------------- attention stats: mz[t] = log2( sum_s exp2(l[t,s]) ) ----------------
// (unchanged from round 9)
__global__ __launch_bounds__(256, 4) void attn_stats(
    const short* __restrict__ Kt, const short* __restrict__ Vt,
    float* __restrict__ mzOut)
{
    const int L = blockIdx.x + 16 * (blockIdx.y + 16 * blockIdx.z);
    const int bh = (L & 7) + 8 * (L >> 7);
    const int t0 = ((L >> 3) & 15) * 64;
    __shared__ short Ks[64 * 64];
    __shared__ short Vs[2][128 * 64];
    const int tid = threadIdx.x;
    const int lane = tid & 63, w = tid >> 6;
    const int q = lane >> 4, c = lane & 15;
    const short* Kbase = Kt + (size_t)bh * 65536;
    const short* Vbase = Vt + (size_t)bh * 65536;

    int vOff[4], vDst[4];
#pragma unroll
    for (int p = 0; p < 4; p++) {
        const int idx = p * 256 + tid;
        const int r = idx >> 3, cs = idx & 7, cg = cs ^ (r & 7);
        vOff[p] = r * 64 + cg * 8;
        vDst[p] = idx * 8;
    }
#pragma unroll
    for (int p = 0; p < 2; p++) {
        const int idx = p * 256 + tid;
        const int r = idx >> 3, cs = idx & 7, cg = cs ^ (r & 7);
        async16(Kbase + (size_t)(t0 + r) * 64 + cg * 8, Ks + idx * 8);
    }
#pragma unroll
    for (int p = 0; p < 4; p++) async16(Vbase + vOff[p], &Vs[0][0] + vDst[p]);

    float z_run[4] = {0.f, 0.f, 0.f, 0.f};

    short8 aK0, aK1;
#pragma unroll 1
    for (int i = 0; i < 8; i++) {
        __syncthreads();
        if (i < 7) {
            const short* src = Vbase + (i + 1) * 8192;
#pragma unroll
            for (int p = 0; p < 4; p++) async16(src + vOff[p], &Vs[(i + 1) & 1][0] + vDst[p]);
        }
        if (i == 0) {
            aK0 = frag64(Ks, w * 16 + c, q);
            aK1 = frag64(Ks, w * 16 + c, 4 + q);
        }
        const short* Vc = &Vs[i & 1][0];
        __builtin_amdgcn_s_setprio(1);
#pragma unroll
        for (int sf = 0; sf < 8; sf++) {
            short8 b0 = frag64(Vc, sf * 16 + c, q);
            short8 b1 = frag64(Vc, sf * 16 + c, 4 + q);
            f32x4 l = {0.f, 0.f, 0.f, 0.f};
            l = MFMA16(aK0, b0, l);
            l = MFMA16(aK1, b1, l);
#pragma unroll
            for (int r = 0; r < 4; r++) z_run[r] += exp2_hw(l[r]);
        }
        __builtin_amdgcn_s_setprio(0);
    }
#pragma unroll
    for (int mask = 1; mask <= 8; mask <<= 1) {
#pragma unroll
        for (int r = 0; r < 4; r++) z_run[r] += __shfl_xor(z_run[r], mask, 64);
    }
    if (c == 0) {
#pragma unroll
        for (int r = 0; r < 4; r++) {
            const int t = t0 + w * 16 + q * 4 + r;
            mzOut[(size_t)bh * Tv + t] = log2_hw(z_run[r]);
        }
    }
}

// ---------------- attention output: s-tile 64, 3 blocks/CU ----------------
// Round-10 change: halve s-tile (128->64) -> grid 1024, LDS 45 KiB -> 3 co-resident
// blocks/CU at independent phases (m114 gap-filling), finer barrier granularity,
// vb regs halved. Math identical to round 9.
__global__ __launch_bounds__(256, 3) void attn_out(
    const short* __restrict__ Qb, const short* __restrict__ Kt, const short* __restrict__ Vt,
    const float* __restrict__ mzIn, float* __restrict__ out)
{
    // XCD remap (bijective, nwg=1024): bh = L&63 (xcd = bh&7), s-block = L>>6.
    const int L = blockIdx.x + 16 * (blockIdx.y + 16 * blockIdx.z);
    const int bh = L & 63;
    const int s0 = (L >> 6) * 64;
    const int b = bh >> 4, h = bh & 15;

    // [0,4096): Vs (prologue) aliased as Pt (main loop)   -- 64s x 64dh, 8 KiB
    // [4096,20480): K/Q double buffer (per buf: Ks 4096 + Qs 4096 shorts)
    // [20480,22528): mz[1024] floats
    __shared__ short smem[22528];
    short* VsPt = smem;
    float* mzs = (float*)(smem + 20480);

    const int tid = threadIdx.x;
    const int lane = tid & 63, w = tid >> 6;
    const int q = lane >> 4, c = lane & 15;
    const short* Vbase = Vt + (size_t)bh * 65536;
    const short* Kbase = Kt + (size_t)bh * 65536;
    const short* Qbase = Qb + (size_t)(b * Tv + h * DHv) * Dv;

    int kOff[2], qOff[2], dK[2], dQ[2];
#pragma unroll
    for (int p = 0; p < 2; p++) {
        const int idx = p * 256 + tid;
        const int r = idx >> 3, cs = idx & 7, cg = cs ^ (r & 7);
        kOff[p] = r * 64 + cg * 8;
        qOff[p] = r * 1024 + cg * 8;
        dK[p] = idx * 8;
        dQ[p] = 4096 + idx * 8;
    }

    // prologue: V(2) + mz(1) + KQ0(4)
#pragma unroll
    for (int p = 0; p < 2; p++) {
        const int idx = p * 256 + tid;
        const int r = idx >> 3, cs = idx & 7, cg = cs ^ (r & 7);
        async16(Vbase + (size_t)(s0 + r) * 64 + cg * 8, VsPt + idx * 8);
    }
    async16(mzIn + (size_t)bh * Tv + tid * 4, (short*)mzs + tid * 8);
#pragma unroll
    for (int p = 0; p < 2; p++) {
        async16(Kbase + kOff[p], smem + 4096 + dK[p]);
        async16(Qbase + qOff[p], smem + 4096 + dQ[p]);
    }
    __syncthreads();

    // V tile -> registers (iteration-invariant MFMA B-operands)
    short8 vb0[4], vb1[4];
#pragma unroll
    for (int sf = 0; sf < 4; sf++) {
        vb0[sf] = frag64(VsPt, sf * 16 + c, q);
        vb1[sf] = frag64(VsPt, sf * 16 + c, 4 + q);
    }

    f32x4 acc[4] = {};
    short* Pt = VsPt;

#pragma unroll 1
    for (int i = 0; i < 16; i++) {
        const short* kq = smem + 4096 + (i & 1) * 8192;
        __syncthreads();   // KQ(i) resident; V-frags read (i==0); Qs/Pt of i-1 consumed
        if (i < 15) {      // prefetch KQ(i+1): in flight across BOTH barriers of this iter
            short* nxt = smem + 4096 + ((i + 1) & 1) * 8192;
            const int t1 = (i + 1) * 64;
#pragma unroll
            for (int p = 0; p < 2; p++) {
                async16(Kbase + t1 * 64 + kOff[p], nxt + dK[p]);
                async16(Qbase + t1 + qOff[p], nxt + dQ[p]);
            }
        }
        // phase A: l = (K*ts*log2e)^T V;  P = exp2(l - mz);  store swizzled Pt
        short8 aK0 = frag64(kq, w * 16 + c, q);
        short8 aK1 = frag64(kq, w * 16 + c, 4 + q);
        const int tr0 = i * 64 + w * 16 + q * 4;
        const float4 mv = *(const float4*)&mzs[tr0];
#pragma unroll
        for (int sf = 0; sf < 4; sf++) {
            f32x4 l = {0.f, 0.f, 0.f, 0.f};
            l = MFMA16(aK0, vb0[sf], l);
            l = MFMA16(aK1, vb1[sf], l);
            const int rr = sf * 16 + c;
            int2v p4;
            p4[0] = cvt_pk_bf16(exp2_hw(l[0] - mv.x), exp2_hw(l[1] - mv.y));
            p4[1] = cvt_pk_bf16(exp2_hw(l[2] - mv.z), exp2_hw(l[3] - mv.w));
            *(int2v*)&Pt[rr * 64 + (((w * 2 + (q >> 1)) ^ (rr & 7)) << 3) + (q & 1) * 4] = p4;
        }
        asm volatile("s_waitcnt lgkmcnt(0)" ::: "memory");
        __builtin_amdgcn_sched_barrier(0);
        __builtin_amdgcn_s_barrier();
        __builtin_amdgcn_sched_barrier(0);
        // phase B: acc += Q * P
        const short* Qs = kq + 4096;
        short8 aQ0 = frag64(Qs, w * 16 + c, q);
        short8 aQ1 = frag64(Qs, w * 16 + c, 4 + q);
        __builtin_amdgcn_s_setprio(1);
#pragma unroll
        for (int sf = 0; sf < 4; sf++) {
            short8 p0 = frag64(Pt, sf * 16 + c, q);
            short8 p1 = frag64(Pt, sf * 16 + c, 4 + q);
            acc[sf] = MFMA16(aQ0, p0, acc[sf]);
            acc[sf] = MFMA16(aQ1, p1, acc[sf]);
        }
        __builtin_amdgcn_s_setprio(0);
    }

#pragma unroll
    for (int sf = 0; sf < 4; sf++) {
#pragma unroll
        for (int r = 0; r < 4; r++) {
            const int d = w * 16 + q * 4 + r;
            out[(size_t)(b * Tv + h * DHv + d) * Dv + s0 + sf * 16 + c] = acc[sf][r];
        }
    }
}

extern "C" void kernel_launch(void* const* d_in, const int* in_sizes, int n_in,
                              void* d_out, int out_size, void* d_ws, size_t ws_size,
                              hipStream_t stream) {
    const float* x    = (const float*)d_in[0];
    const float* Wq   = (const float*)d_in[1];
    const float* bq   = (const float*)d_in[2];
    const float* Wk   = (const float*)d_in[3];
    const float* bk   = (const float*)d_in[4];
    const float* Wv   = (const float*)d_in[5];
    const float* bv   = (const float*)d_in[6];
    const float* temp = (const float*)d_in[7];
    float* out = (float*)d_out;

    char* ws = (char*)d_ws;
    short* xp = (short*)(ws);                       // [0, 8M)   packed x panels
    short* Wp = (short*)(ws + ((size_t)8 << 20));   // [8M, 14M) packed W panels (3z)
    short* Qb = (short*)(ws + ((size_t)14 << 20));  // [14M, 22M)
    short* Kt = (short*)(ws + ((size_t)22 << 20));  // [22M, 30M)
    short* Vt = (short*)(ws + ((size_t)30 << 20));  // [30M, 38M)
    float* mzbuf = (float*)(ws + ((size_t)38 << 20));

    prep<<<2816, 256, 0, stream>>>(x, Wq, Wk, Wv, xp, Wp);
    qkv_mfma<<<dim3(16, 32), 256, 0, stream>>>(xp, Wp, bq, bk, bv, temp, Qb, Kt, Vt);
    attn_stats<<<dim3(16, 16, 4), 256, 0, stream>>>(Kt, Vt, mzbuf);
    attn_out<<<dim3(16, 16, 4), 256, 0, stream>>>(Qb, Kt, Vt, mzbuf, out);
}

// Round 11
// 151.657 us; speedup vs baseline: 1.0635x; 1.0635x over previous
//
#include <hip/hip_runtime.h>
#include <math.h>

#define Bv 4
#define Tv 1024
#define Dv 1024
#define Hv 16
#define DHv 64
#define L2E 1.4426950408889634f

typedef __attribute__((ext_vector_type(8))) short short8;
typedef __attribute__((ext_vector_type(4))) short short4v;
typedef __attribute__((ext_vector_type(4))) float f32x4;
typedef __attribute__((ext_vector_type(2))) int int2v;

#define MFMA16(a, b, c) __builtin_amdgcn_mfma_f32_16x16x32_bf16((a), (b), (c), 0, 0, 0)

__device__ __forceinline__ short f2bf(float f) {
    union { float f; unsigned u; } v; v.f = f;
    unsigned r = v.u + 0x7FFFu + ((v.u >> 16) & 1u);
    return (short)(r >> 16);
}

// hardware exp2/log2 via compiler-known builtins (proper TRANS-hazard modeling)
__device__ __forceinline__ float exp2_hw(float x) {
#if __has_builtin(__builtin_amdgcn_exp2f)
    return __builtin_amdgcn_exp2f(x);
#else
    return exp2f(x);
#endif
}
__device__ __forceinline__ float log2_hw(float x) {
#if __has_builtin(__builtin_amdgcn_logf)
    return __builtin_amdgcn_logf(x);
#else
    return log2f(x);
#endif
}

// packed bf16 convert (RTNE, same rounding as f2bf). Non-TRANS VOP3: no hazard class.
__device__ __forceinline__ int cvt_pk_bf16(float lo, float hi) {
    int r; asm("v_cvt_pk_bf16_f32 %0, %1, %2" : "=v"(r) : "v"(lo), "v"(hi)); return r;
}

__device__ __forceinline__ void async16(const void* g, void* l) {
    __builtin_amdgcn_global_load_lds(
        (const __attribute__((address_space(1))) void*)g,
        (__attribute__((address_space(3))) void*)l, 16, 0, 0);
}

// Fragment read from a 64-short-wide tile stored with chunk-XOR swizzle
// (chunk cw of row r lives at slot cw ^ (r&7)). 2-way bank aliasing only.
__device__ __forceinline__ short8 frag64(const short* buf, int r, int cw) {
    return *(const short8*)&buf[r * 64 + ((cw ^ (r & 7)) << 3)];
}

// 32-short-wide (BK=32) variant: 4 chunks per row, slot = (cw ^ (r>>1)) & 3.
__device__ __forceinline__ short8 frag32(const short* buf, int r, int cw) {
    return *(const short8*)&buf[r * 32 + (((cw ^ (r >> 1)) & 3) << 3)];
}

// ---------------- cast x -> packed bf16 K-panels: xp[kb][t][32] ----------------
__global__ __launch_bounds__(256) void cast_x(const float* __restrict__ x, short* __restrict__ xp) {
    const int idx = blockIdx.x * 256 + threadIdx.x;
    const int t = idx >> 7, j = idx & 127;
    const float* src = x + (size_t)t * 1024 + j * 8;
    float4 f0 = ((const float4*)src)[0], f1 = ((const float4*)src)[1];
    short8 o;
    o[0] = f2bf(f0.x); o[1] = f2bf(f0.y); o[2] = f2bf(f0.z); o[3] = f2bf(f0.w);
    o[4] = f2bf(f1.x); o[5] = f2bf(f1.y); o[6] = f2bf(f1.z); o[7] = f2bf(f1.w);
    *(short8*)&xp[(j >> 2) * 131072 + t * 32 + (j & 3) * 8] = o;
}

// ---------------- cast + transpose W -> packed panels Wp[z][kb][n][32] ----------------
__global__ __launch_bounds__(256) void w_cast_t(
    const float* __restrict__ Wq, const float* __restrict__ Wk, const float* __restrict__ Wv,
    short* __restrict__ Wt)
{
    const float* W = (blockIdx.z == 0) ? Wq : (blockIdx.z == 1) ? Wk : Wv;
    short* Wto = Wt + (size_t)blockIdx.z * 1048576;
    __shared__ short Tl[64 * 72];
    const int k0 = blockIdx.y * 64, n0 = blockIdx.x * 64;
    const int tid = threadIdx.x;
    {
        const int r = tid >> 2, c16 = (tid & 3) * 16;
        const float* src = W + (size_t)(k0 + r) * Dv + n0 + c16;
        float4 f0 = ((const float4*)src)[0], f1 = ((const float4*)src)[1];
        float4 f2 = ((const float4*)src)[2], f3 = ((const float4*)src)[3];
        short8 s0, s1;
        s0[0] = f2bf(f0.x); s0[1] = f2bf(f0.y); s0[2] = f2bf(f0.z); s0[3] = f2bf(f0.w);
        s0[4] = f2bf(f1.x); s0[5] = f2bf(f1.y); s0[6] = f2bf(f1.z); s0[7] = f2bf(f1.w);
        s1[0] = f2bf(f2.x); s1[1] = f2bf(f2.y); s1[2] = f2bf(f2.z); s1[3] = f2bf(f2.w);
        s1[4] = f2bf(f3.x); s1[5] = f2bf(f3.y); s1[6] = f2bf(f3.z); s1[7] = f2bf(f3.w);
        *(short8*)&Tl[r * 72 + c16] = s0;
        *(short8*)&Tl[r * 72 + c16 + 8] = s1;
    }
    __syncthreads();
#pragma unroll
    for (int p = 0; p < 2; p++) {
        const int n = p * 32 + (tid >> 3), j8 = (tid & 7) * 8;
        short8 o;
#pragma unroll
        for (int jj = 0; jj < 8; jj++) o[jj] = Tl[(j8 + jj) * 72 + n];
        const int kk = k0 + j8;
        *(short8*)&Wto[(kk >> 5) * 32768 + (size_t)(n0 + n) * 32 + (kk & 31)] = o;
    }
}

// ---------------- QKV projection: merged-z 128x64 tile, BK=32, 2 blocks/CU ----------------
// R9 structure (154.0 us baseline) + T1 XCD remap: tm0 = L&31 so the 16 blocks sharing
// one 256 KB x-panel satisfy L===tm0 (mod 8) -> same XCD L2 (round-6 FETCH showed ~8 MB
// of cross-XCD panel re-fetch; this recovers it). Pure bijective index permutation.
__global__ __launch_bounds__(256, 2) void qkv_mfma(
    const short* __restrict__ xp, const short* __restrict__ Wp,
    const float* __restrict__ bq, const float* __restrict__ bk, const float* __restrict__ bv,
    const float* __restrict__ temp,
    short* __restrict__ Qo, short* __restrict__ Kt, short* __restrict__ Vt)
{
    __shared__ short smem[30720];                // 3 slots x 10240 shorts = 60 KiB

    const int tid = threadIdx.x;
    const int lane = tid & 63, w = tid >> 6;
    const int q = lane >> 4, c = lane & 15;
    const int wr = w >> 1, wc = w & 1;           // 2x2 wave grid: 64 tok x 32 feat each
    const int L = blockIdx.x + 16 * blockIdx.y;  // [0, 512)
    const int n0 = (L >> 5) * 64;                // 16 feature-blocks
    const int tm0 = (L & 31) * 128;              // 32 token-blocks; xcd = tm0-block & 7

    int aOff[2];
#pragma unroll
    for (int p = 0; p < 2; p++) {
        const int idx = p * 256 + tid;
        const int r = idx >> 2, cs = idx & 3, cg = (cs ^ (r >> 1)) & 3;
        aOff[p] = (tm0 + r) * 32 + cg * 8;
    }
    const int br = tid >> 2, bcs = tid & 3, bcg = (bcs ^ (br >> 1)) & 3;
    const int bOff = (n0 + br) * 32 + bcg * 8;

    f32x4 acc[3][4][2] = {};

    auto stage = [&](int s, int kb) {            // 5 loads/thread: A x2 + B x3
        short* base = smem + s * 10240;
#pragma unroll
        for (int p = 0; p < 2; p++)
            async16(xp + kb * 131072 + aOff[p], base + (p * 256 + tid) * 8);
#pragma unroll
        for (int z = 0; z < 3; z++)
            async16(Wp + z * 1048576 + kb * 32768 + bOff,
                    base + 4096 + z * 2048 + tid * 8);
    };
    auto compute = [&](int s) {
        const short* base = smem + s * 10240;
        short8 af[4];
#pragma unroll
        for (int m = 0; m < 4; m++) af[m] = frag32(base, wr * 64 + m * 16 + c, q);
        __builtin_amdgcn_s_setprio(1);
#pragma unroll
        for (int z = 0; z < 3; z++) {
            const short* Bz = base + 4096 + z * 2048;
            short8 b0 = frag32(Bz, wc * 32 + c, q);
            short8 b1 = frag32(Bz, wc * 32 + 16 + c, q);
#pragma unroll
            for (int m = 0; m < 4; m++) {
                acc[z][m][0] = MFMA16(af[m], b0, acc[z][m][0]);
                acc[z][m][1] = MFMA16(af[m], b1, acc[z][m][1]);
            }
        }
        __builtin_amdgcn_s_setprio(0);
    };

    stage(0, 0); stage(1, 1);                    // 10 loads (2 tiles) in flight

#pragma unroll 1
    for (int i = 0; i < 30; i++) {
        asm volatile("s_waitcnt vmcnt(5)" ::: "memory");   // tile i resident; i+1 in flight
        __builtin_amdgcn_s_barrier();
        __builtin_amdgcn_sched_barrier(0);
        stage((i + 2) % 3, i + 2);
        compute(i % 3);
    }
    asm volatile("s_waitcnt vmcnt(5)" ::: "memory");
    __builtin_amdgcn_s_barrier();
    __builtin_amdgcn_sched_barrier(0);
    compute(30 % 3);
    asm volatile("s_waitcnt vmcnt(0)" ::: "memory");
    __builtin_amdgcn_s_barrier();
    __builtin_amdgcn_sched_barrier(0);
    compute(31 % 3);

#pragma unroll
    for (int jn = 0; jn < 2; jn++) {
        const int col = n0 + wc * 32 + jn * 16 + c;
        const float bb = bq[col];
#pragma unroll
        for (int m = 0; m < 4; m++)
#pragma unroll
            for (int rr = 0; rr < 4; rr++) {
                const int row = tm0 + wr * 64 + m * 16 + q * 4 + rr;
                Qo[(size_t)row * Dv + col] = f2bf(acc[0][m][jn][rr] + bb);
            }
    }
    const int hb = tm0 >> 6;
#pragma unroll
    for (int z = 1; z < 3; z++) {
        const float* bias = (z == 1) ? bk : bv;
        short* dst = (z == 1) ? Kt : Vt;
        float scl = 1.f;
        if (z == 1) scl = temp[(hb + wr) & 15] * L2E;
        __syncthreads();
        short* T = smem;
#pragma unroll
        for (int jn = 0; jn < 2; jn++) {
            const int nl = wc * 32 + jn * 16 + c;
            const float bb = bias[n0 + nl];
#pragma unroll
            for (int m = 0; m < 4; m++) {
                int2v pk;
                pk[0] = cvt_pk_bf16((acc[z][m][jn][0] + bb) * scl, (acc[z][m][jn][1] + bb) * scl);
                pk[1] = cvt_pk_bf16((acc[z][m][jn][2] + bb) * scl, (acc[z][m][jn][3] + bb) * scl);
                *(int2v*)&T[nl * 136 + wr * 64 + m * 16 + q * 4] = pk;
            }
        }
        __syncthreads();
#pragma unroll
        for (int p = 0; p < 4; p++) {
            const int idx = p * 256 + tid;
            const int n = idx >> 4, k2 = idx & 15;
            short8 v = *(const short8*)&T[n * 136 + k2 * 8];
            const size_t addr = (size_t)(hb + (k2 >> 3)) * 65536 +
                                (size_t)(n0 + n) * 64 + (k2 & 7) * 8;
            *(short8*)&dst[addr] = v;
        }
    }
}

// ---------------- attention stats: mz[t] = log2( sum_s exp2(l[t,s]) ) ----------------
__global__ __launch_bounds__(256, 4) void attn_stats(
    const short* __restrict__ Kt, const short* __restrict__ Vt,
    float* __restrict__ mzOut)
{
    const int L = blockIdx.x + 16 * (blockIdx.y + 16 * blockIdx.z);
    const int bh = (L & 7) + 8 * (L >> 7);
    const int t0 = ((L >> 3) & 15) * 64;
    __shared__ short Ks[64 * 64];
    __shared__ short Vs[2][128 * 64];
    const int tid = threadIdx.x;
    const int lane = tid & 63, w = tid >> 6;
    const int q = lane >> 4, c = lane & 15;
    const short* Kbase = Kt + (size_t)bh * 65536;
    const short* Vbase = Vt + (size_t)bh * 65536;

    int vOff[4], vDst[4];
#pragma unroll
    for (int p = 0; p < 4; p++) {
        const int idx = p * 256 + tid;
        const int r = idx >> 3, cs = idx & 7, cg = cs ^ (r & 7);
        vOff[p] = r * 64 + cg * 8;
        vDst[p] = idx * 8;
    }
#pragma unroll
    for (int p = 0; p < 2; p++) {
        const int idx = p * 256 + tid;
        const int r = idx >> 3, cs = idx & 7, cg = cs ^ (r & 7);
        async16(Kbase + (size_t)(t0 + r) * 64 + cg * 8, Ks + idx * 8);
    }
#pragma unroll
    for (int p = 0; p < 4; p++) async16(Vbase + vOff[p], &Vs[0][0] + vDst[p]);

    float z_run[4] = {0.f, 0.f, 0.f, 0.f};

    short8 aK0, aK1;
#pragma unroll 1
    for (int i = 0; i < 8; i++) {
        __syncthreads();
        if (i < 7) {
            const short* src = Vbase + (i + 1) * 8192;
#pragma unroll
            for (int p = 0; p < 4; p++) async16(src + vOff[p], &Vs[(i + 1) & 1][0] + vDst[p]);
        }
        if (i == 0) {
            aK0 = frag64(Ks, w * 16 + c, q);
            aK1 = frag64(Ks, w * 16 + c, 4 + q);
        }
        const short* Vc = &Vs[i & 1][0];
        __builtin_amdgcn_s_setprio(1);
#pragma unroll
        for (int sf = 0; sf < 8; sf++) {
            short8 b0 = frag64(Vc, sf * 16 + c, q);
            short8 b1 = frag64(Vc, sf * 16 + c, 4 + q);
            f32x4 l = {0.f, 0.f, 0.f, 0.f};
            l = MFMA16(aK0, b0, l);
            l = MFMA16(aK1, b1, l);
#pragma unroll
            for (int r = 0; r < 4; r++) z_run[r] += exp2_hw(l[r]);
        }
        __builtin_amdgcn_s_setprio(0);
    }
#pragma unroll
    for (int mask = 1; mask <= 8; mask <<= 1) {
#pragma unroll
        for (int r = 0; r < 4; r++) z_run[r] += __shfl_xor(z_run[r], mask, 64);
    }
    if (c == 0) {
#pragma unroll
        for (int r = 0; r < 4; r++) {
            const int t = t0 + w * 16 + q * 4 + r;
            mzOut[(size_t)bh * Tv + t] = log2_hw(z_run[r]);
        }
    }
}

// ---------------- attention output: P = exp2(l - mz), pipelined K/Q, V in regs ----------------
// (R9 version: s-tile 128 -- R10's s-tile-64 split regressed; reverted)
__global__ __launch_bounds__(256, 2) void attn_out(
    const short* __restrict__ Qb, const short* __restrict__ Kt, const short* __restrict__ Vt,
    const float* __restrict__ mzIn, float* __restrict__ out)
{
    const int L = blockIdx.x + 8 * (blockIdx.y + 16 * blockIdx.z);
    const int bh = (L & 7) + 8 * (L >> 6);
    const int s0 = ((L >> 3) & 7) * 128;
    const int b = bh >> 4, h = bh & 15;

    __shared__ short smem[26624];
    short* VsPt = smem;
    float* mzs = (float*)(smem + 24576);

    const int tid = threadIdx.x;
    const int lane = tid & 63, w = tid >> 6;
    const int q = lane >> 4, c = lane & 15;
    const short* Vbase = Vt + (size_t)bh * 65536;
    const short* Kbase = Kt + (size_t)bh * 65536;
    const short* Qbase = Qb + (size_t)(b * Tv + h * DHv) * Dv;

    int kOff[2], qOff[2], dK[2], dQ[2];
#pragma unroll
    for (int p = 0; p < 2; p++) {
        const int idx = p * 256 + tid;
        const int r = idx >> 3, cs = idx & 7, cg = cs ^ (r & 7);
        kOff[p] = r * 64 + cg * 8;
        qOff[p] = r * 1024 + cg * 8;
        dK[p] = idx * 8;
        dQ[p] = 4096 + idx * 8;
    }

#pragma unroll
    for (int p = 0; p < 4; p++) {
        const int idx = p * 256 + tid;
        const int r = idx >> 3, cs = idx & 7, cg = cs ^ (r & 7);
        async16(Vbase + (size_t)(s0 + r) * 64 + cg * 8, VsPt + idx * 8);
    }
    async16(mzIn + (size_t)bh * Tv + tid * 4, (short*)mzs + tid * 8);
#pragma unroll
    for (int p = 0; p < 2; p++) {
        async16(Kbase + kOff[p], smem + 8192 + dK[p]);
        async16(Qbase + qOff[p], smem + 8192 + dQ[p]);
    }
    __syncthreads();

    short8 vb0[8], vb1[8];
#pragma unroll
    for (int sf = 0; sf < 8; sf++) {
        vb0[sf] = frag64(VsPt, sf * 16 + c, q);
        vb1[sf] = frag64(VsPt, sf * 16 + c, 4 + q);
    }

    f32x4 acc[8] = {};
    short* Pt = VsPt;

#pragma unroll 1
    for (int i = 0; i < 16; i++) {
        const short* kq = smem + 8192 + (i & 1) * 8192;
        __syncthreads();
        if (i < 15) {
            short* nxt = smem + 8192 + ((i + 1) & 1) * 8192;
            const int t1 = (i + 1) * 64;
#pragma unroll
            for (int p = 0; p < 2; p++) {
                async16(Kbase + t1 * 64 + kOff[p], nxt + dK[p]);
                async16(Qbase + t1 + qOff[p], nxt + dQ[p]);
            }
        }
        short8 aK0 = frag64(kq, w * 16 + c, q);
        short8 aK1 = frag64(kq, w * 16 + c, 4 + q);
        const int tr0 = i * 64 + w * 16 + q * 4;
        const float4 mv = *(const float4*)&mzs[tr0];
#pragma unroll
        for (int sf = 0; sf < 8; sf++) {
            f32x4 l = {0.f, 0.f, 0.f, 0.f};
            l = MFMA16(aK0, vb0[sf], l);
            l = MFMA16(aK1, vb1[sf], l);
            const int rr = sf * 16 + c;
            int2v p4;
            p4[0] = cvt_pk_bf16(exp2_hw(l[0] - mv.x), exp2_hw(l[1] - mv.y));
            p4[1] = cvt_pk_bf16(exp2_hw(l[2] - mv.z), exp2_hw(l[3] - mv.w));
            *(int2v*)&Pt[rr * 64 + (((w * 2 + (q >> 1)) ^ (rr & 7)) << 3) + (q & 1) * 4] = p4;
        }
        asm volatile("s_waitcnt lgkmcnt(0)" ::: "memory");
        __builtin_amdgcn_sched_barrier(0);
        __builtin_amdgcn_s_barrier();
        __builtin_amdgcn_sched_barrier(0);
        const short* Qs = kq + 4096;
        short8 aQ0 = frag64(Qs, w * 16 + c, q);
        short8 aQ1 = frag64(Qs, w * 16 + c, 4 + q);
        __builtin_amdgcn_s_setprio(1);
#pragma unroll
        for (int sf = 0; sf < 8; sf++) {
            short8 p0 = frag64(Pt, sf * 16 + c, q);
            short8 p1 = frag64(Pt, sf * 16 + c, 4 + q);
            acc[sf] = MFMA16(aQ0, p0, acc[sf]);
            acc[sf] = MFMA16(aQ1, p1, acc[sf]);
        }
        __builtin_amdgcn_s_setprio(0);
    }

#pragma unroll
    for (int sf = 0; sf < 8; sf++) {
#pragma unroll
        for (int r = 0; r < 4; r++) {
            const int d = w * 16 + q * 4 + r;
            out[(size_t)(b * Tv + h * DHv + d) * Dv + s0 + sf * 16 + c] = acc[sf][r];
        }
    }
}

extern "C" void kernel_launch(void* const* d_in, const int* in_sizes, int n_in,
                              void* d_out, int out_size, void* d_ws, size_t ws_size,
                              hipStream_t stream) {
    const float* x    = (const float*)d_in[0];
    const float* Wq   = (const float*)d_in[1];
    const float* bq   = (const float*)d_in[2];
    const float* Wk   = (const float*)d_in[3];
    const float* bk   = (const float*)d_in[4];
    const float* Wv   = (const float*)d_in[5];
    const float* bv   = (const float*)d_in[6];
    const float* temp = (const float*)d_in[7];
    float* out = (float*)d_out;

    char* ws = (char*)d_ws;
    short* xp = (short*)(ws);                       // [0, 8M)   packed x panels
    short* Wp = (short*)(ws + ((size_t)8 << 20));   // [8M, 14M) packed W panels (3z)
    short* Qb = (short*)(ws + ((size_t)14 << 20));  // [14M, 22M)
    short* Kt = (short*)(ws + ((size_t)22 << 20));  // [22M, 30M)
    short* Vt = (short*)(ws + ((size_t)30 << 20));  // [30M, 38M)
    float* mzbuf = (float*)(ws + ((size_t)38 << 20));

    cast_x<<<2048, 256, 0, stream>>>(x, xp);
    w_cast_t<<<dim3(16, 16, 3), 256, 0, stream>>>(Wq, Wk, Wv, Wp);
    qkv_mfma<<<dim3(16, 32), 256, 0, stream>>>(xp, Wp, bq, bk, bv, temp, Qb, Kt, Vt);
    attn_stats<<<dim3(16, 16, 4), 256, 0, stream>>>(Kt, Vt, mzbuf);
    attn_out<<<dim3(8, 16, 4), 256, 0, stream>>>(Qb, Kt, Vt, mzbuf, out);
}